// Round 13
// baseline (110.735 us; speedup 1.0000x reference)
//
#include <hip/hip_runtime.h>
#include <cstdint>

#define NA_N 50000
#define NB_N 50000
#define NE_N 800000
#define DD 256
#define GEMM_NBLK 1563           // (NB_N+31)/32
#define RS_NBLK   3125           // (NE_N+255)/256
#define SA_NBLK   3125           // (NA_N+15)/16

using bf8   = __attribute__((ext_vector_type(8))) short;   // 8 bf16 = 4 VGPR
using f32x4 = __attribute__((ext_vector_type(4))) float;
using u16x8 = __attribute__((ext_vector_type(8))) ushort;

__device__ __forceinline__ ushort f2bf(float f) {
    uint u = __float_as_uint(f);
    uint r = (u + 0x7fffu + ((u >> 16) & 1u)) >> 16;       // RNE
    return (ushort)r;
}
__device__ __forceinline__ float bf2f(ushort u) {
    return __uint_as_float(((uint)u) << 16);
}

// ------- prep: wt_cast (16 blocks) + rowstart (3125) + s_a rowdot (3125) -------
// LDS 16.6 KB -> 9 blocks/CU; streaming tail runs at BW, unlike the r12 fat-gemm.
__global__ __launch_bounds__(256) void prep_k(const float* __restrict__ W,
    ushort* __restrict__ Wt, const int* __restrict__ esrc,
    int* __restrict__ row_start, const float* __restrict__ fa,
    const float* __restrict__ a_top, float* __restrict__ s_a)
{
    __shared__ float T[64][65];
    if (blockIdx.x < 16) {                     // ---- W transpose+cast ----
        const int bi = blockIdx.x & 3;
        const int bj = blockIdx.x >> 2;
        const int lane = threadIdx.x & 63, w = threadIdx.x >> 6;
        for (int i = w; i < 64; i += 4)
            T[i][lane] = W[(size_t)(bi * 64 + i) * DD + bj * 64 + lane];
        __syncthreads();
        for (int i = w; i < 64; i += 4)
            Wt[(size_t)(bj * 64 + i) * DD + bi * 64 + lane] = f2bf(T[lane][i]);
        return;
    }
    if (blockIdx.x < 16 + RS_NBLK) {           // ---- row_start builder ----
        int e = (blockIdx.x - 16) * 256 + threadIdx.x;
        if (e >= NE_N) return;
        int s    = esrc[e];
        int prev = (e == 0) ? -1 : esrc[e - 1];
        for (int r = prev + 1; r <= s; r++) row_start[r] = e;
        if (e == NE_N - 1)
            for (int r = s + 1; r <= NA_N; r++) row_start[r] = NE_N;
        return;
    }
    // ---- s_a rowdot: 16 rows/block, 16 lanes/row ----
    const int t   = threadIdx.x;
    const int row = (blockIdx.x - 16 - RS_NBLK) * 16 + (t >> 4);
    if (row >= NA_N) return;
    const f32x4* fr = (const f32x4*)(fa + (size_t)row * DD) + (t & 15) * 4;
    const f32x4* tv = (const f32x4*)a_top + (t & 15) * 4;
    float p = 0.f;
#pragma unroll
    for (int j = 0; j < 4; j++) {
        f32x4 x = fr[j], y = tv[j];
        p += x[0] * y[0] + x[1] * y[1] + x[2] * y[2] + x[3] * y[3];
    }
    p += __shfl_xor(p, 1, 64); p += __shfl_xor(p, 2, 64);
    p += __shfl_xor(p, 4, 64); p += __shfl_xor(p, 8, 64);
    if ((t & 15) == 0) s_a[row] = p;
}

// ------- GEMM BM=32: emb_b = bf16(fb)@W + bias ; fused s_b = emb@a_bot -------
// 17.4 KB LDS -> 9 blocks/CU (was 4 at BM=64); 1563 blocks kills the 3.05/CU
// quantization tail. B-frags software-pipelined 1 ks-step ahead.
__global__ __launch_bounds__(256) void gemm_mfma(
    const float* __restrict__ A, const ushort* __restrict__ Wt,
    const float* __restrict__ bias, const float* __restrict__ a_bot,
    ushort* __restrict__ C, float* __restrict__ s_b)
{
    __shared__ ushort As[32 * 264];
    __shared__ float  sdot[4][32];
    const int t  = threadIdx.x;
    const int r0 = blockIdx.x * 32;

#pragma unroll
    for (int i = 0; i < 8; i++) {
        int flat = i * 256 + t;
        int row  = flat >> 6;
        int c4   = flat & 63;
        int gr   = r0 + row; if (gr >= NB_N) gr = 0;      // clamp tail
        float4 v = ((const float4*)(A + (size_t)gr * DD))[c4];
        ushort4 b;
        b.x = f2bf(v.x); b.y = f2bf(v.y); b.z = f2bf(v.z); b.w = f2bf(v.w);
        *(ushort4*)&As[row * 264 + c4 * 4] = b;
    }
    __syncthreads();

    const int lane = t & 63;
    const int wv   = t >> 6;
    const int lr   = lane & 15;
    const int lk   = (lane >> 4) * 8;
    const ushort* Wb = Wt + (size_t)(wv * 64 + lr) * DD + lk;

    f32x4 acc[2][4];
#pragma unroll
    for (int m = 0; m < 2; m++)
#pragma unroll
        for (int n = 0; n < 4; n++) acc[m][n] = (f32x4){0.f, 0.f, 0.f, 0.f};

    bf8 bbc[4], bbn[4];
#pragma unroll
    for (int n = 0; n < 4; n++)                       // preload ks=0 B-frags
        bbc[n] = *(const bf8*)(Wb + (size_t)n * 16 * DD);

#pragma unroll
    for (int ks = 0; ks < 8; ks++) {
        const int k0 = ks * 32;
        if (ks < 7) {
#pragma unroll
            for (int n = 0; n < 4; n++)               // prefetch ks+1 B-frags
                bbn[n] = *(const bf8*)(Wb + (size_t)n * 16 * DD + k0 + 32);
        }
        bf8 af[2];
#pragma unroll
        for (int m = 0; m < 2; m++)
            af[m] = *(const bf8*)&As[(m * 16 + lr) * 264 + k0 + lk];
#pragma unroll
        for (int m = 0; m < 2; m++)
#pragma unroll
            for (int n = 0; n < 4; n++)
                acc[m][n] = __builtin_amdgcn_mfma_f32_16x16x32_bf16(
                    af[m], bbc[n], acc[m][n], 0, 0, 0);
#pragma unroll
        for (int n = 0; n < 4; n++) bbc[n] = bbn[n];  // static rotation
    }

    float abv[4];
#pragma unroll
    for (int n = 0; n < 4; n++) abv[n] = a_bot[wv * 64 + n * 16 + lr];

    float part[2][4];
#pragma unroll
    for (int m = 0; m < 2; m++)
#pragma unroll
        for (int r = 0; r < 4; r++) part[m][r] = 0.f;

#pragma unroll
    for (int m = 0; m < 2; m++)
#pragma unroll
        for (int n = 0; n < 4; n++) {
            int   col = wv * 64 + n * 16 + lr;
            float bv  = bias[col];
#pragma unroll
            for (int r = 0; r < 4; r++) {
                int   rowg = r0 + m * 16 + (lane >> 4) * 4 + r;  // C: col=lane&15, row=(lane>>4)*4+r
                float v    = acc[m][n][r] + bv;
                if (rowg < NB_N) C[(size_t)rowg * DD + col] = f2bf(v);
                part[m][r] = fmaf(v, abv[n], part[m][r]);
            }
        }

#pragma unroll
    for (int m = 0; m < 2; m++)
#pragma unroll
        for (int r = 0; r < 4; r++) {
#pragma unroll
            for (int off = 1; off < 16; off <<= 1)
                part[m][r] += __shfl_xor(part[m][r], off, 64);
        }
    if (lr == 0) {
#pragma unroll
        for (int m = 0; m < 2; m++)
#pragma unroll
            for (int r = 0; r < 4; r++)
                sdot[wv][m * 16 + (lane >> 4) * 4 + r] = part[m][r];
    }
    __syncthreads();
    if (t < 32) {
        int rowg = r0 + t;
        if (rowg < NB_N)
            s_b[rowg] = sdot[0][t] + sdot[1][t] + sdot[2][t] + sdot[3][t];
    }
}

// -------- edge aggregation: wave/row, quarter-wave/edge, depth-2 software pipeline --------
__global__ __launch_bounds__(256) void edge_agg8(
    const int* __restrict__ edst, const int* __restrict__ row_start,
    const float* __restrict__ s_a, const float* __restrict__ sb,
    const ushort* __restrict__ emb, float* __restrict__ out)
{
    const int lane = threadIdx.x & 63;
    const int a    = blockIdx.x * 4 + (threadIdx.x >> 6);
    if (a >= NA_N) return;

    const float sa_a = s_a[a];
    const int g = lane >> 4;          // quarter-wave group: one edge per stage
    const int c = lane & 15;          // 16-col block within row
    const int beg = row_start[a], end = row_start[a + 1];

    float accA[8], accB[8];
#pragma unroll
    for (int j = 0; j < 8; j++) { accA[j] = 0.f; accB[j] = 0.f; }
    float rs = 0.f;

    if (beg < end) {
        const int last = end - 1;

        int   pc  = beg + g;                      // current-stage position
        int   pn  = pc + 4;                       // next-stage position
        int   dc  = edst[min(pc, last)];
        int   dn  = edst[min(pn, last)];
        float sbc = sb[dc];
        float sbn = sb[dn];
        const ushort* rc = emb + (size_t)dc * DD + c * 16;
        u16x8 ua = *(const u16x8*)rc;             // stage-0 gathers in flight
        u16x8 ub = *(const u16x8*)(rc + 8);

#pragma unroll 2
        for (int e = beg; e < end; e += 4) {
            // issue next-stage gathers (independent of current consumption)
            const ushort* rn = emb + (size_t)dn * DD + c * 16;
            u16x8 na = *(const u16x8*)rn;
            u16x8 nb = *(const u16x8*)(rn + 8);
            // preload stage+2 index & sb
            int   p2  = pn + 4;
            int   d2  = edst[min(p2, last)];
            float sb2 = sb[d2];

            // score for current stage
            float lg = sa_a + sbc;
            float el = lg > 0.f ? lg : 0.1f * (__expf(lg) - 1.f);
            float s  = (pc < end) ? __expf(el) : 0.f;

            // consume current gathers (waits only on ua/ub — older loads)
#pragma unroll
            for (int j = 0; j < 8; j++) {
                accA[j] = fmaf(s, bf2f(ua[j]), accA[j]);
                accB[j] = fmaf(s, bf2f(ub[j]), accB[j]);
            }
            rs += s;

            // rotate pipeline (pure renaming after unroll)
            pc = pn;  dc = dn;  sbc = sbn;
            ua = na;  ub = nb;
            pn = p2;  dn = d2;  sbn = sb2;
        }
    }

    // combine the 4 quarter-wave partials (xor over group bits 16,32)
#pragma unroll
    for (int j = 0; j < 8; j++) {
        accA[j] += __shfl_xor(accA[j], 16, 64);
        accA[j] += __shfl_xor(accA[j], 32, 64);
        accB[j] += __shfl_xor(accB[j], 16, 64);
        accB[j] += __shfl_xor(accB[j], 32, 64);
    }
    rs += __shfl_xor(rs, 16, 64);
    rs += __shfl_xor(rs, 32, 64);

    if (g == 0) {                      // lanes 0-15 write cols c*16..c*16+15
        const float inv = (rs == 0.f) ? 1.f : (1.f / rs);
        float* op = out + (size_t)a * DD + c * 16;
        float4 o0 = { accA[0] * inv, accA[1] * inv, accA[2] * inv, accA[3] * inv };
        float4 o1 = { accA[4] * inv, accA[5] * inv, accA[6] * inv, accA[7] * inv };
        float4 o2 = { accB[0] * inv, accB[1] * inv, accB[2] * inv, accB[3] * inv };
        float4 o3 = { accB[4] * inv, accB[5] * inv, accB[6] * inv, accB[7] * inv };
        *(float4*)(op + 0)  = o0;
        *(float4*)(op + 4)  = o1;
        *(float4*)(op + 8)  = o2;
        *(float4*)(op + 12) = o3;
    }
}

extern "C" void kernel_launch(void* const* d_in, const int* in_sizes, int n_in,
                              void* d_out, int out_size, void* d_ws, size_t ws_size,
                              hipStream_t stream)
{
    const float* fa   = (const float*)d_in[0];
    const float* fb   = (const float*)d_in[1];
    const float* W    = (const float*)d_in[2];
    const float* bias = (const float*)d_in[3];
    const float* avec = (const float*)d_in[4];
    const int*   esrc = (const int*)d_in[5];
    const int*   edst = (const int*)d_in[6];
    float*       out  = (float*)d_out;

    char*   ws        = (char*)d_ws;
    ushort* emb_b     = (ushort*)ws;                               // 25.6 MB
    float*  s_b       = (float*)(ws + (size_t)NB_N * DD * 2);      // NB
    int*    row_start = (int*)(s_b + NB_N);                        // NA+1
    float*  s_a       = (float*)(row_start + NA_N + 2);            // NA
    ushort* Wt        = (ushort*)(s_a + NA_N);                     // 128 KB

    prep_k   <<<16 + RS_NBLK + SA_NBLK, 256, 0, stream>>>(
        W, Wt, esrc, row_start, fa, avec, s_a);
    gemm_mfma<<<GEMM_NBLK, 256, 0, stream>>>(fb, Wt, bias, avec + DD,
                                             emb_b, s_b);
    edge_agg8<<<(NA_N + 3) / 4, 256, 0, stream>>>(edst, row_start, s_a,
                                                  s_b, emb_b, out);
}

// Round 14
// 105.083 us; speedup vs baseline: 1.0538x; 1.0538x over previous
//
#include <hip/hip_runtime.h>
#include <cstdint>

#define NA_N 50000
#define NB_N 50000
#define NE_N 800000
#define DD 256
#define GEMM_NBLK 782            // (NB_N+63)/64
#define WT_NBLK   32
#define RS_NBLK   3125           // (NE_N+255)/256
#define SA_NBLK   3125           // (NA_N+15)/16

using bf8   = __attribute__((ext_vector_type(8))) short;   // 8 bf16 = 4 VGPR
using f32x4 = __attribute__((ext_vector_type(4))) float;
using u16x8 = __attribute__((ext_vector_type(8))) ushort;

__device__ __forceinline__ ushort f2bf(float f) {
    uint u = __float_as_uint(f);
    uint r = (u + 0x7fffu + ((u >> 16) & 1u)) >> 16;       // RNE
    return (ushort)r;
}
__device__ __forceinline__ float bf2f(ushort u) {
    return __uint_as_float(((uint)u) << 16);
}

// ------- prep (ZERO LDS -> full occupancy for the streaming blocks) -------
// blocks 0-31:        Wt[n][k] = bf16(W[k][n])  (coalesced reads, 16B scattered writes)
// blocks 32..3156:    row_start[] from sorted esrc
// blocks 3157..6281:  s_a[i] = dot(fa[i,:], a_top)  (51 MB stream at HBM BW)
__global__ __launch_bounds__(256) void prep_k(const float* __restrict__ W,
    ushort* __restrict__ Wt, const int* __restrict__ esrc,
    int* __restrict__ row_start, const float* __restrict__ fa,
    const float* __restrict__ a_top, float* __restrict__ s_a)
{
    const int t = threadIdx.x;
    if (blockIdx.x < WT_NBLK) {                // ---- W transpose+cast, k-slab of 8 ----
        const int k0 = blockIdx.x * 8;
        u16x8 pack;
#pragma unroll
        for (int j = 0; j < 8; j++)
            pack[j] = f2bf(W[(size_t)(k0 + j) * DD + t]);   // coalesced across t
        *(u16x8*)(Wt + (size_t)t * DD + k0) = pack;         // Wt[n=t][k0..k0+7]
        return;
    }
    if (blockIdx.x < WT_NBLK + RS_NBLK) {      // ---- row_start builder ----
        int e = (blockIdx.x - WT_NBLK) * 256 + t;
        if (e >= NE_N) return;
        int s    = esrc[e];
        int prev = (e == 0) ? -1 : esrc[e - 1];
        for (int r = prev + 1; r <= s; r++) row_start[r] = e;
        if (e == NE_N - 1)
            for (int r = s + 1; r <= NA_N; r++) row_start[r] = NE_N;
        return;
    }
    // ---- s_a rowdot: 16 rows/block, 16 lanes/row ----
    const int row = (blockIdx.x - WT_NBLK - RS_NBLK) * 16 + (t >> 4);
    if (row >= NA_N) return;
    const f32x4* fr = (const f32x4*)(fa + (size_t)row * DD) + (t & 15) * 4;
    const f32x4* tv = (const f32x4*)a_top + (t & 15) * 4;
    float p = 0.f;
#pragma unroll
    for (int j = 0; j < 4; j++) {
        f32x4 x = fr[j], y = tv[j];
        p += x[0] * y[0] + x[1] * y[1] + x[2] * y[2] + x[3] * y[3];
    }
    p += __shfl_xor(p, 1, 64); p += __shfl_xor(p, 2, 64);
    p += __shfl_xor(p, 4, 64); p += __shfl_xor(p, 8, 64);
    if ((t & 15) == 0) s_a[row] = p;
}

// ------- GEMM BM=64 (r11 body): emb_b = bf16(fb)@W + bias ; fused s_b = emb@a_bot -------
// B-frags software-pipelined 1 ks-step ahead (hides L2 latency under 16-MFMA cluster).
__global__ __launch_bounds__(256) void gemm_mfma(
    const float* __restrict__ A, const ushort* __restrict__ Wt,
    const float* __restrict__ bias, const float* __restrict__ a_bot,
    ushort* __restrict__ C, float* __restrict__ s_b)
{
    __shared__ ushort As[64 * 264];
    __shared__ float  sdot[4][64];
    const int t  = threadIdx.x;
    const int r0 = blockIdx.x * 64;

#pragma unroll
    for (int i = 0; i < 16; i++) {
        int flat = i * 256 + t;
        int row  = flat >> 6;
        int c4   = flat & 63;
        int gr   = r0 + row; if (gr >= NB_N) gr = 0;      // clamp tail
        float4 v = ((const float4*)(A + (size_t)gr * DD))[c4];
        ushort4 b;
        b.x = f2bf(v.x); b.y = f2bf(v.y); b.z = f2bf(v.z); b.w = f2bf(v.w);
        *(ushort4*)&As[row * 264 + c4 * 4] = b;
    }
    __syncthreads();

    const int lane = t & 63;
    const int wv   = t >> 6;
    const int lr   = lane & 15;
    const int lk   = (lane >> 4) * 8;
    const ushort* Wb = Wt + (size_t)(wv * 64 + lr) * DD + lk;

    f32x4 acc[4][4];
#pragma unroll
    for (int m = 0; m < 4; m++)
#pragma unroll
        for (int n = 0; n < 4; n++) acc[m][n] = (f32x4){0.f, 0.f, 0.f, 0.f};

    bf8 bbc[4], bbn[4];
#pragma unroll
    for (int n = 0; n < 4; n++)                       // preload ks=0 B-frags
        bbc[n] = *(const bf8*)(Wb + (size_t)n * 16 * DD);

#pragma unroll
    for (int ks = 0; ks < 8; ks++) {
        const int k0 = ks * 32;
        if (ks < 7) {
#pragma unroll
            for (int n = 0; n < 4; n++)               // prefetch ks+1 B-frags
                bbn[n] = *(const bf8*)(Wb + (size_t)n * 16 * DD + k0 + 32);
        }
        bf8 af[4];
#pragma unroll
        for (int m = 0; m < 4; m++)
            af[m] = *(const bf8*)&As[(m * 16 + lr) * 264 + k0 + lk];
#pragma unroll
        for (int m = 0; m < 4; m++)
#pragma unroll
            for (int n = 0; n < 4; n++)
                acc[m][n] = __builtin_amdgcn_mfma_f32_16x16x32_bf16(
                    af[m], bbc[n], acc[m][n], 0, 0, 0);
#pragma unroll
        for (int n = 0; n < 4; n++) bbc[n] = bbn[n];  // static rotation
    }

    float abv[4];
#pragma unroll
    for (int n = 0; n < 4; n++) abv[n] = a_bot[wv * 64 + n * 16 + lr];

    float part[4][4];
#pragma unroll
    for (int m = 0; m < 4; m++)
#pragma unroll
        for (int r = 0; r < 4; r++) part[m][r] = 0.f;

#pragma unroll
    for (int m = 0; m < 4; m++)
#pragma unroll
        for (int n = 0; n < 4; n++) {
            int   col = wv * 64 + n * 16 + lr;
            float bv  = bias[col];
#pragma unroll
            for (int r = 0; r < 4; r++) {
                int   rowg = r0 + m * 16 + (lane >> 4) * 4 + r;  // C: col=lane&15, row=(lane>>4)*4+r
                float v    = acc[m][n][r] + bv;
                if (rowg < NB_N) C[(size_t)rowg * DD + col] = f2bf(v);
                part[m][r] = fmaf(v, abv[n], part[m][r]);
            }
        }

#pragma unroll
    for (int m = 0; m < 4; m++)
#pragma unroll
        for (int r = 0; r < 4; r++) {
#pragma unroll
            for (int off = 1; off < 16; off <<= 1)
                part[m][r] += __shfl_xor(part[m][r], off, 64);
        }
    if (lr == 0) {
#pragma unroll
        for (int m = 0; m < 4; m++)
#pragma unroll
            for (int r = 0; r < 4; r++)
                sdot[wv][m * 16 + (lane >> 4) * 4 + r] = part[m][r];
    }
    __syncthreads();
    if (t < 64) {
        int rowg = r0 + t;
        if (rowg < NB_N)
            s_b[rowg] = sdot[0][t] + sdot[1][t] + sdot[2][t] + sdot[3][t];
    }
}

// -------- edge aggregation: wave/row, quarter-wave/edge, depth-2 software pipeline --------
__global__ __launch_bounds__(256) void edge_agg8(
    const int* __restrict__ edst, const int* __restrict__ row_start,
    const float* __restrict__ s_a, const float* __restrict__ sb,
    const ushort* __restrict__ emb, float* __restrict__ out)
{
    const int lane = threadIdx.x & 63;
    const int a    = blockIdx.x * 4 + (threadIdx.x >> 6);
    if (a >= NA_N) return;

    const float sa_a = s_a[a];
    const int g = lane >> 4;          // quarter-wave group: one edge per stage
    const int c = lane & 15;          // 16-col block within row
    const int beg = row_start[a], end = row_start[a + 1];

    float accA[8], accB[8];
#pragma unroll
    for (int j = 0; j < 8; j++) { accA[j] = 0.f; accB[j] = 0.f; }
    float rs = 0.f;

    if (beg < end) {
        const int last = end - 1;

        int   pc  = beg + g;                      // current-stage position
        int   pn  = pc + 4;                       // next-stage position
        int   dc  = edst[min(pc, last)];
        int   dn  = edst[min(pn, last)];
        float sbc = sb[dc];
        float sbn = sb[dn];
        const ushort* rc = emb + (size_t)dc * DD + c * 16;
        u16x8 ua = *(const u16x8*)rc;             // stage-0 gathers in flight
        u16x8 ub = *(const u16x8*)(rc + 8);

#pragma unroll 2
        for (int e = beg; e < end; e += 4) {
            // issue next-stage gathers (independent of current consumption)
            const ushort* rn = emb + (size_t)dn * DD + c * 16;
            u16x8 na = *(const u16x8*)rn;
            u16x8 nb = *(const u16x8*)(rn + 8);
            // preload stage+2 index & sb
            int   p2  = pn + 4;
            int   d2  = edst[min(p2, last)];
            float sb2 = sb[d2];

            // score for current stage
            float lg = sa_a + sbc;
            float el = lg > 0.f ? lg : 0.1f * (__expf(lg) - 1.f);
            float s  = (pc < end) ? __expf(el) : 0.f;

            // consume current gathers (waits only on ua/ub — older loads)
#pragma unroll
            for (int j = 0; j < 8; j++) {
                accA[j] = fmaf(s, bf2f(ua[j]), accA[j]);
                accB[j] = fmaf(s, bf2f(ub[j]), accB[j]);
            }
            rs += s;

            // rotate pipeline (pure renaming after unroll)
            pc = pn;  dc = dn;  sbc = sbn;
            ua = na;  ub = nb;
            pn = p2;  dn = d2;  sbn = sb2;
        }
    }

    // combine the 4 quarter-wave partials (xor over group bits 16,32)
#pragma unroll
    for (int j = 0; j < 8; j++) {
        accA[j] += __shfl_xor(accA[j], 16, 64);
        accA[j] += __shfl_xor(accA[j], 32, 64);
        accB[j] += __shfl_xor(accB[j], 16, 64);
        accB[j] += __shfl_xor(accB[j], 32, 64);
    }
    rs += __shfl_xor(rs, 16, 64);
    rs += __shfl_xor(rs, 32, 64);

    if (g == 0) {                      // lanes 0-15 write cols c*16..c*16+15
        const float inv = (rs == 0.f) ? 1.f : (1.f / rs);
        float* op = out + (size_t)a * DD + c * 16;
        float4 o0 = { accA[0] * inv, accA[1] * inv, accA[2] * inv, accA[3] * inv };
        float4 o1 = { accA[4] * inv, accA[5] * inv, accA[6] * inv, accA[7] * inv };
        float4 o2 = { accB[0] * inv, accB[1] * inv, accB[2] * inv, accB[3] * inv };
        float4 o3 = { accB[4] * inv, accB[5] * inv, accB[6] * inv, accB[7] * inv };
        *(float4*)(op + 0)  = o0;
        *(float4*)(op + 4)  = o1;
        *(float4*)(op + 8)  = o2;
        *(float4*)(op + 12) = o3;
    }
}

extern "C" void kernel_launch(void* const* d_in, const int* in_sizes, int n_in,
                              void* d_out, int out_size, void* d_ws, size_t ws_size,
                              hipStream_t stream)
{
    const float* fa   = (const float*)d_in[0];
    const float* fb   = (const float*)d_in[1];
    const float* W    = (const float*)d_in[2];
    const float* bias = (const float*)d_in[3];
    const float* avec = (const float*)d_in[4];
    const int*   esrc = (const int*)d_in[5];
    const int*   edst = (const int*)d_in[6];
    float*       out  = (float*)d_out;

    char*   ws        = (char*)d_ws;
    ushort* emb_b     = (ushort*)ws;                               // 25.6 MB
    float*  s_b       = (float*)(ws + (size_t)NB_N * DD * 2);      // NB
    int*    row_start = (int*)(s_b + NB_N);                        // NA+1
    float*  s_a       = (float*)(row_start + NA_N + 2);            // NA
    ushort* Wt        = (ushort*)(s_a + NA_N);                     // 128 KB

    prep_k   <<<WT_NBLK + RS_NBLK + SA_NBLK, 256, 0, stream>>>(
        W, Wt, esrc, row_start, fa, avec, s_a);
    gemm_mfma<<<GEMM_NBLK, 256, 0, stream>>>(fb, Wt, bias, avec + DD,
                                             emb_b, s_b);
    edge_agg8<<<(NA_N + 3) / 4, 256, 0, stream>>>(edst, row_start, s_a,
                                                  s_b, emb_b, out);
}